// Round 1
// baseline (1585.967 us; speedup 1.0000x reference)
//
#include <hip/hip_runtime.h>
#include <cstdint>

#define NROW 6144
#define HDIM 512
#define DOUT 256
#define NEG_INF (-__builtin_inff())

typedef _Float16 half8 __attribute__((ext_vector_type(8)));
typedef _Float16 half4v __attribute__((ext_vector_type(4)));
typedef float f32x4 __attribute__((ext_vector_type(4)));

__device__ __forceinline__ void gld_lds16(void* lds, const void* g) {
  __builtin_amdgcn_global_load_lds(
      (const __attribute__((address_space(1))) void*)g,
      (__attribute__((address_space(3))) void*)lds, 16, 0, 0);
}

// ---------------- GEMM: C[M,N] = A[M,K] * B[N,K]^T  (both row-major, f16 in, f32 acc)
// epilogue: v = acc * (rowscale? rowscale[row]:1) + (bias? bias[col]:0); writes f32 and/or f16
__global__ __launch_bounds__(256)
void gemm_f16(const _Float16* __restrict__ A, int lda,
              const _Float16* __restrict__ B, int ldb,
              float* __restrict__ Cf, _Float16* __restrict__ Ch, int ldc,
              const float* __restrict__ bias, const float* __restrict__ rowscale,
              int K)
{
  __shared__ _Float16 As[128][32];
  __shared__ _Float16 Bs[128][32];
  const int tid = threadIdx.x;
  const int wave = tid >> 6, lane = tid & 63;
  const int wr = wave >> 1, wc = wave & 1;
  const int row0 = blockIdx.x * 128, col0 = blockIdx.y * 128;

  const int sr = lane >> 2;        // staging: row within 16-row group
  const int sk = (lane & 3) * 8;   // staging: k offset (8 halves = 16B)

  f32x4 acc[4][4];
  const f32x4 vzero = {0.f, 0.f, 0.f, 0.f};
  #pragma unroll
  for (int i = 0; i < 4; ++i)
    #pragma unroll
    for (int j = 0; j < 4; ++j)
      acc[i][j] = vzero;

  const int fr = lane & 15;
  const int fk = (lane >> 4) * 8;

  for (int k0 = 0; k0 < K; k0 += 32) {
    #pragma unroll
    for (int c = 0; c < 2; ++c) {
      int rbase = c * 64 + wave * 16;  // wave-uniform LDS base; HW adds lane*16B
      gld_lds16(&As[rbase][0], A + (size_t)(row0 + rbase + sr) * lda + k0 + sk);
      gld_lds16(&Bs[rbase][0], B + (size_t)(col0 + rbase + sr) * ldb + k0 + sk);
    }
    __syncthreads();
    half8 af[4], bf[4];
    #pragma unroll
    for (int i = 0; i < 4; ++i)
      af[i] = *(const half8*)&As[wr * 64 + i * 16 + fr][fk];
    #pragma unroll
    for (int j = 0; j < 4; ++j)
      bf[j] = *(const half8*)&Bs[wc * 64 + j * 16 + fr][fk];
    #pragma unroll
    for (int i = 0; i < 4; ++i)
      #pragma unroll
      for (int j = 0; j < 4; ++j)
        acc[i][j] = __builtin_amdgcn_mfma_f32_16x16x32_f16(af[i], bf[j], acc[i][j], 0, 0, 0);
    __syncthreads();
  }

  const int lr = (lane >> 4) * 4;   // C/D layout: col=lane&15, row=(lane>>4)*4+reg (m89)
  const int lc = lane & 15;
  #pragma unroll
  for (int i = 0; i < 4; ++i) {
    #pragma unroll
    for (int j = 0; j < 4; ++j) {
      #pragma unroll
      for (int r = 0; r < 4; ++r) {
        int row = row0 + wr * 64 + i * 16 + lr + r;
        int col = col0 + wc * 64 + j * 16 + lc;
        float v = acc[i][j][r];
        if (rowscale) v *= rowscale[row];
        if (bias) v += bias[col];
        if (Cf) Cf[(size_t)row * ldc + col] = v;
        if (Ch) Ch[(size_t)row * ldc + col] = (_Float16)v;
      }
    }
  }
}

// ---------------- degree -> dis = d>0 ? rsqrt(max(d,1e-12)) : 0
__global__ __launch_bounds__(256)
void degree_kernel(const float* __restrict__ A, float* __restrict__ dis)
{
  const int row = blockIdx.x;
  const float* a = A + (size_t)row * NROW;
  float s = 0.f;
  #pragma unroll
  for (int it = 0; it < 6; ++it) {
    int j = it * 1024 + threadIdx.x * 4;
    float4 v = *(const float4*)&a[j];
    s += v.x + v.y + v.z + v.w;
  }
  #pragma unroll
  for (int off = 32; off; off >>= 1) s += __shfl_xor(s, off);
  __shared__ float red[4];
  if ((threadIdx.x & 63) == 0) red[threadIdx.x >> 6] = s;
  __syncthreads();
  if (threadIdx.x == 0) {
    float d = red[0] + red[1] + red[2] + red[3];
    dis[row] = (d > 0.f) ? rsqrtf(fmaxf(d, 1e-12f)) : 0.f;
  }
}

// ---------------- f32 -> f16 convert with scale
__global__ __launch_bounds__(256)
void convert_f16(const float* __restrict__ x, _Float16* __restrict__ y, float scale, long n4)
{
  for (long i = (long)blockIdx.x * 256 + threadIdx.x; i < n4; i += (long)gridDim.x * 256) {
    float4 v = ((const float4*)x)[i];
    half4v o;
    o[0] = (_Float16)(v.x * scale);
    o[1] = (_Float16)(v.y * scale);
    o[2] = (_Float16)(v.z * scale);
    o[3] = (_Float16)(v.w * scale);
    ((half4v*)y)[i] = o;
  }
}

// ---------------- dst[c][r] = f16(src[r][c] * rowscale[r]); src f32 [R,C], dst [C,R]
__global__ __launch_bounds__(256)
void transpose_scale_f16(const float* __restrict__ src, const float* __restrict__ rowscale,
                         _Float16* __restrict__ dst, int R, int C)
{
  __shared__ _Float16 tile[64][72];
  const int c0 = blockIdx.x * 64, r0 = blockIdx.y * 64;
  const int tx4 = (threadIdx.x & 15) * 4, ty = threadIdx.x >> 4;
  #pragma unroll
  for (int p = 0; p < 4; ++p) {
    int r = p * 16 + ty;
    float4 v = *(const float4*)&src[(size_t)(r0 + r) * C + c0 + tx4];
    float sc = rowscale ? rowscale[r0 + r] : 1.0f;
    tile[tx4 + 0][r] = (_Float16)(v.x * sc);
    tile[tx4 + 1][r] = (_Float16)(v.y * sc);
    tile[tx4 + 2][r] = (_Float16)(v.z * sc);
    tile[tx4 + 3][r] = (_Float16)(v.w * sc);
  }
  __syncthreads();
  #pragma unroll
  for (int p = 0; p < 4; ++p) {
    int c = p * 16 + ty;
    half4v o;
    o[0] = tile[c][tx4 + 0];
    o[1] = tile[c][tx4 + 1];
    o[2] = tile[c][tx4 + 2];
    o[3] = tile[c][tx4 + 3];
    *(half4v*)&dst[(size_t)(c0 + c) * R + r0 + tx4] = o;
  }
}

// ---------------- dst[c][r] = src[r*ld + c]; src f16, dst [C,R]
__global__ __launch_bounds__(256)
void transpose_f16(const _Float16* __restrict__ src, int ld,
                   _Float16* __restrict__ dst, int R, int C)
{
  __shared__ _Float16 tile[64][72];
  const int c0 = blockIdx.x * 64, r0 = blockIdx.y * 64;
  const int tx4 = (threadIdx.x & 15) * 4, ty = threadIdx.x >> 4;
  #pragma unroll
  for (int p = 0; p < 4; ++p) {
    int r = p * 16 + ty;
    half4v v = *(const half4v*)&src[(size_t)(r0 + r) * ld + c0 + tx4];
    tile[tx4 + 0][r] = v[0];
    tile[tx4 + 1][r] = v[1];
    tile[tx4 + 2][r] = v[2];
    tile[tx4 + 3][r] = v[3];
  }
  __syncthreads();
  #pragma unroll
  for (int p = 0; p < 4; ++p) {
    int c = p * 16 + ty;
    half4v o;
    o[0] = tile[c][tx4 + 0];
    o[1] = tile[c][tx4 + 1];
    o[2] = tile[c][tx4 + 2];
    o[3] = tile[c][tx4 + 3];
    *(half4v*)&dst[(size_t)(c0 + c) * R + r0 + tx4] = o;
  }
}

// ---------------- masked row softmax: P[row0+b][:] = softmax(S[b][:] masked by adj)
__global__ __launch_bounds__(256)
void softmax_mask(const float* __restrict__ S, const float* __restrict__ adj,
                  _Float16* __restrict__ P, int row0)
{
  const int lrow = blockIdx.x;
  const int grow = row0 + lrow;
  const float* s = S + (size_t)lrow * NROW;
  const float* a = adj + (size_t)grow * NROW;
  _Float16* p = P + (size_t)grow * NROW;
  const int tid = threadIdx.x;
  float v[24];
  float m = NEG_INF;
  #pragma unroll
  for (int it = 0; it < 6; ++it) {
    int j = it * 1024 + tid * 4;
    float4 sv = *(const float4*)&s[j];
    float4 av = *(const float4*)&a[j];
    float x0 = (av.x != 0.f) ? sv.x : NEG_INF;
    float x1 = (av.y != 0.f) ? sv.y : NEG_INF;
    float x2 = (av.z != 0.f) ? sv.z : NEG_INF;
    float x3 = (av.w != 0.f) ? sv.w : NEG_INF;
    v[it * 4 + 0] = x0; v[it * 4 + 1] = x1; v[it * 4 + 2] = x2; v[it * 4 + 3] = x3;
    m = fmaxf(m, fmaxf(fmaxf(x0, x1), fmaxf(x2, x3)));
  }
  #pragma unroll
  for (int off = 32; off; off >>= 1) m = fmaxf(m, __shfl_xor(m, off));
  __shared__ float red[4];
  const int lane = tid & 63, wave = tid >> 6;
  if (lane == 0) red[wave] = m;
  __syncthreads();
  m = fmaxf(fmaxf(red[0], red[1]), fmaxf(red[2], red[3]));
  if (m == NEG_INF) {  // fully masked row (never in practice) -> zeros
    #pragma unroll
    for (int it = 0; it < 6; ++it) {
      int j = it * 1024 + tid * 4;
      half4v o; o[0] = (_Float16)0.f; o[1] = (_Float16)0.f; o[2] = (_Float16)0.f; o[3] = (_Float16)0.f;
      *(half4v*)&p[j] = o;
    }
    return;
  }
  float l = 0.f;
  #pragma unroll
  for (int k = 0; k < 24; ++k) { float e = __expf(v[k] - m); v[k] = e; l += e; }
  #pragma unroll
  for (int off = 32; off; off >>= 1) l += __shfl_xor(l, off);
  __syncthreads();
  if (lane == 0) red[wave] = l;
  __syncthreads();
  l = red[0] + red[1] + red[2] + red[3];
  float inv = 1.f / l;
  #pragma unroll
  for (int it = 0; it < 6; ++it) {
    int j = it * 1024 + tid * 4;
    half4v o;
    o[0] = (_Float16)(v[it * 4 + 0] * inv);
    o[1] = (_Float16)(v[it * 4 + 1] * inv);
    o[2] = (_Float16)(v[it * 4 + 2] * inv);
    o[3] = (_Float16)(v[it * 4 + 3] * inv);
    *(half4v*)&p[j] = o;
  }
}

// ---------------- BN: per-column partial sums over 128-row slices
__global__ __launch_bounds__(256)
void bn_partial(const float* __restrict__ X, int C,
                float* __restrict__ psum, float* __restrict__ psq)
{
  const int b = blockIdx.x;
  const int tid = threadIdx.x;
  const float* x = X + (size_t)b * 128 * C;
  float s0 = 0, q0 = 0, s1 = 0, q1 = 0;
  for (int r = 0; r < 128; ++r) {
    float a = x[(size_t)r * C + tid];
    s0 += a; q0 += a * a;
    if (C == 512) {
      float c2 = x[(size_t)r * C + tid + 256];
      s1 += c2; q1 += c2 * c2;
    }
  }
  psum[b * C + tid] = s0; psq[b * C + tid] = q0;
  if (C == 512) { psum[b * C + tid + 256] = s1; psq[b * C + tid + 256] = q1; }
}

__global__ void bn_finalize(const float* __restrict__ psum, const float* __restrict__ psq,
                            int C, const float* __restrict__ g, const float* __restrict__ beta,
                            float* __restrict__ scale, float* __restrict__ shift)
{
  int c = threadIdx.x + blockIdx.x * blockDim.x;
  if (c >= C) return;
  float s = 0, q = 0;
  for (int b = 0; b < 48; ++b) { s += psum[b * C + c]; q += psq[b * C + c]; }
  const float invN = 1.0f / 6144.0f;
  float mean = s * invN;
  float var = q * invN - mean * mean;
  float rstd = rsqrtf(fmaxf(var, 0.f) + 1e-5f);
  float sc = g[c] * rstd;
  scale[c] = sc;
  shift[c] = beta[c] - mean * sc;
}

// ---------------- y = relu?(x*scale[c]+shift[c]) + residual; writes f32 and/or f16
__global__ __launch_bounds__(256)
void bn_apply(const float* __restrict__ X, const float* __restrict__ scale,
              const float* __restrict__ shift, const float* __restrict__ residual,
              float* __restrict__ Yf, _Float16* __restrict__ Yh,
              int Cmask, long total, int do_relu)
{
  for (long i = (long)blockIdx.x * 256 + threadIdx.x; i < total; i += (long)gridDim.x * 256) {
    int c = (int)(i & Cmask);
    float v = X[i] * scale[c] + shift[c];
    if (do_relu) v = fmaxf(v, 0.f);
    if (residual) v += residual[i];
    if (Yf) Yf[i] = v;
    if (Yh) Yh[i] = (_Float16)v;
  }
}

extern "C" void kernel_launch(void* const* d_in, const int* in_sizes, int n_in,
                              void* d_out, int out_size, void* d_ws, size_t ws_size,
                              hipStream_t stream)
{
  (void)in_sizes; (void)n_in; (void)out_size; (void)ws_size;
  const float* X     = (const float*)d_in[0];
  const float* adj   = (const float*)d_in[1];
  const float* adjg  = (const float*)d_in[2];
  const float* Wp    = (const float*)d_in[3];
  const float* bp    = (const float*)d_in[4];
  const float* gp    = (const float*)d_in[5];
  const float* betap = (const float*)d_in[6];

  float* out_h     = (float*)d_out;                       // [6144,256]
  float* out_embed = out_h + (size_t)NROW * DOUT;         // [6144,512]

  char* base = (char*)d_ws;
  size_t off = 0;
  auto alloc = [&](size_t bytes) -> void* {
    void* p = base + off;
    off += (bytes + 255) & ~(size_t)255;
    return p;
  };

  _Float16* Ag    = (_Float16*)alloc((size_t)NROW * NROW * 2);   // 75.5 MB; reused as Pfull
  _Float16* Pfull = Ag;
  float*    Sc    = (float*)alloc((size_t)1536 * NROW * 4);      // 37.7 MB score chunk
  _Float16* XsT   = (_Float16*)alloc((size_t)HDIM * NROW * 2);
  _Float16* Yh    = (_Float16*)alloc((size_t)NROW * HDIM * 2);
  _Float16* Wph   = (_Float16*)alloc((size_t)HDIM * HDIM * 2);
  _Float16* QKVW[3];
  for (int i = 0; i < 3; ++i) QKVW[i] = (_Float16*)alloc((size_t)1536 * HDIM * 2);
  _Float16* Woh[3];
  Woh[0] = (_Float16*)alloc((size_t)512 * 512 * 2);
  Woh[1] = (_Float16*)alloc((size_t)512 * 512 * 2);
  Woh[2] = (_Float16*)alloc((size_t)256 * 512 * 2);
  _Float16* QKVh = (_Float16*)alloc((size_t)NROW * 1536 * 2);
  _Float16* VTh  = (_Float16*)alloc((size_t)HDIM * NROW * 2);
  _Float16* AVh  = (_Float16*)alloc((size_t)NROW * HDIM * 2);
  float* xbuf = (float*)alloc((size_t)NROW * HDIM * 4);
  float* hA   = (float*)alloc((size_t)NROW * HDIM * 4);
  float* hB   = (float*)alloc((size_t)NROW * HDIM * 4);
  _Float16* hb16 = (_Float16*)alloc((size_t)NROW * HDIM * 2);
  float* dis  = (float*)alloc((size_t)NROW * 4);
  float* psum = (float*)alloc((size_t)48 * 512 * 4);
  float* psq  = (float*)alloc((size_t)48 * 512 * 4);
  float* bnsc = (float*)alloc(512 * 4);
  float* bnsh = (float*)alloc(512 * 4);

  const float qk_scale = 0.21022410381342863f;  // 512^(-1/4); applied to both Wq and Wk

  degree_kernel<<<NROW, 256, 0, stream>>>(adjg, dis);
  convert_f16<<<2048, 256, 0, stream>>>(adjg, Ag, 1.f, (long)NROW * NROW / 4);
  transpose_scale_f16<<<dim3(8, 96), 256, 0, stream>>>(X, dis, XsT, NROW, HDIM);
  convert_f16<<<256, 256, 0, stream>>>(Wp, Wph, 1.f, 512 * 512 / 4);
  for (int i = 0; i < 3; ++i) {
    const float* Wq = (const float*)d_in[7 + i * 7 + 0];
    const float* Wk = (const float*)d_in[7 + i * 7 + 1];
    const float* Wv = (const float*)d_in[7 + i * 7 + 2];
    const float* Wo = (const float*)d_in[7 + i * 7 + 3];
    int o = (i < 2) ? 512 : 256;
    convert_f16<<<256, 256, 0, stream>>>(Wq, QKVW[i], qk_scale, 512 * 512 / 4);
    convert_f16<<<256, 256, 0, stream>>>(Wk, QKVW[i] + 512 * 512, qk_scale, 512 * 512 / 4);
    convert_f16<<<256, 256, 0, stream>>>(Wv, QKVW[i] + 2 * 512 * 512, 1.f, 512 * 512 / 4);
    convert_f16<<<256, 256, 0, stream>>>(Wo, Woh[i], 1.f, (long)o * 512 / 4);
  }

  // ---- embedding: h = BN( (D^-1/2 Aglo D^-1/2) X Wp^T + bp )
  gemm_f16<<<dim3(48, 4), 256, 0, stream>>>(Ag, NROW, XsT, NROW, nullptr, Yh, HDIM,
                                            nullptr, dis, NROW);
  gemm_f16<<<dim3(48, 4), 256, 0, stream>>>(Yh, HDIM, Wph, HDIM, xbuf, nullptr, HDIM,
                                            bp, nullptr, HDIM);
  bn_partial<<<48, 256, 0, stream>>>(xbuf, 512, psum, psq);
  bn_finalize<<<2, 256, 0, stream>>>(psum, psq, 512, gp, betap, bnsc, bnsh);
  bn_apply<<<2048, 256, 0, stream>>>(xbuf, bnsc, bnsh, nullptr, out_embed, hb16,
                                     511, (long)NROW * 512, 0);

  float* hcur = out_embed;
  for (int i = 0; i < 3; ++i) {
    int o = (i < 2) ? 512 : 256;
    const float* bo = (const float*)d_in[7 + i * 7 + 4];
    const float* gl = (const float*)d_in[7 + i * 7 + 5];
    const float* bl = (const float*)d_in[7 + i * 7 + 6];

    // QKV fused projection: [6144,1536]
    gemm_f16<<<dim3(48, 12), 256, 0, stream>>>(hb16, HDIM, QKVW[i], HDIM, nullptr, QKVh, 1536,
                                               nullptr, nullptr, HDIM);
    transpose_f16<<<dim3(8, 96), 256, 0, stream>>>(QKVh + 1024, 1536, VTh, NROW, HDIM);
    // scores + masked softmax, 4 chunks of 1536 rows
    for (int c = 0; c < 4; ++c) {
      const _Float16* Qc = QKVh + (size_t)c * 1536 * 1536;
      gemm_f16<<<dim3(12, 48), 256, 0, stream>>>(Qc, 1536, QKVh + 512, 1536, Sc, nullptr, NROW,
                                                 nullptr, nullptr, HDIM);
      softmax_mask<<<1536, 256, 0, stream>>>(Sc, adj, Pfull, c * 1536);
    }
    // attn @ V
    gemm_f16<<<dim3(48, 4), 256, 0, stream>>>(Pfull, NROW, VTh, NROW, nullptr, AVh, HDIM,
                                              nullptr, nullptr, NROW);
    // @ Wo^T + bo
    gemm_f16<<<dim3(48, o / 128), 256, 0, stream>>>(AVh, HDIM, Woh[i], HDIM, xbuf, nullptr, o,
                                                    bo, nullptr, HDIM);
    bn_partial<<<48, 256, 0, stream>>>(xbuf, o, psum, psq);
    bn_finalize<<<2, 256, 0, stream>>>(psum, psq, o, gl, bl, bnsc, bnsh);
    if (i < 2) {
      float* hnext = (i == 0) ? hA : hB;
      bn_apply<<<2048, 256, 0, stream>>>(xbuf, bnsc, bnsh, hcur, hnext, hb16,
                                         o - 1, (long)NROW * o, 1);
      hcur = hnext;
    } else {
      bn_apply<<<2048, 256, 0, stream>>>(xbuf, bnsc, bnsh, nullptr, out_h, nullptr,
                                         o - 1, (long)NROW * o, 1);
    }
  }
}

// Round 2
// 989.587 us; speedup vs baseline: 1.6027x; 1.6027x over previous
//
#include <hip/hip_runtime.h>
#include <cstdint>

#define NROW 6144
#define HDIM 512
#define DOUT 256
#define NEG_INF (-__builtin_inff())

typedef _Float16 half8 __attribute__((ext_vector_type(8)));
typedef _Float16 half4v __attribute__((ext_vector_type(4)));
typedef float f32x4 __attribute__((ext_vector_type(4)));

__device__ __forceinline__ void gld_lds16(void* lds, const void* g) {
  __builtin_amdgcn_global_load_lds(
      (const __attribute__((address_space(1))) void*)g,
      (__attribute__((address_space(3))) void*)lds, 16, 0, 0);
}

// ---------------- GEMM: C[M,N] = A[M,K] * B[N,K]^T  (row-major, f16 in, f32 acc)
// LDS is XOR-swizzled: physical slot p (16B) of row r holds logical slot p ^ ((r&15)>>1 & 3).
// Staging pre-swizzles the GLOBAL source k-offset (global_load_lds writes linearly);
// fragment reads apply the same swizzle -> conflict-free half8 ds_reads.
// If Pk != null: split-K mode, store f16 partial at Pk[z*MN + row*ldc + col].
__global__ __launch_bounds__(256)
void gemm_f16(const _Float16* __restrict__ A, int lda,
              const _Float16* __restrict__ B, int ldb,
              float* __restrict__ Cf, _Float16* __restrict__ Ch, int ldc,
              int Kc, _Float16* __restrict__ Pk, long MN)
{
  __shared__ _Float16 As[128][32];
  __shared__ _Float16 Bs[128][32];
  const int tid = threadIdx.x;
  const int wave = tid >> 6, lane = tid & 63;
  const int wr = wave >> 1, wc = wave & 1;
  const int row0 = blockIdx.x * 128, col0 = blockIdx.y * 128;
  const int kbase = blockIdx.z * Kc;

  const int sr = lane >> 2;                                  // staging row in 16-row group
  const int sk = ((lane & 3) ^ ((lane >> 3) & 3)) * 8;       // pre-swizzled k slot (halves)

  f32x4 acc[4][4];
  const f32x4 vzero = {0.f, 0.f, 0.f, 0.f};
  #pragma unroll
  for (int i = 0; i < 4; ++i)
    #pragma unroll
    for (int j = 0; j < 4; ++j)
      acc[i][j] = vzero;

  const int fr = lane & 15;
  const int fk = (((lane >> 4) ^ ((fr >> 1) & 3))) * 8;      // swizzled read slot

  for (int k0 = kbase; k0 < kbase + Kc; k0 += 32) {
    #pragma unroll
    for (int c = 0; c < 2; ++c) {
      int rbase = c * 64 + wave * 16;  // wave-uniform LDS base; HW adds lane*16B
      gld_lds16(&As[rbase][0], A + (size_t)(row0 + rbase + sr) * lda + k0 + sk);
      gld_lds16(&Bs[rbase][0], B + (size_t)(col0 + rbase + sr) * ldb + k0 + sk);
    }
    __syncthreads();
    half8 af[4], bf[4];
    #pragma unroll
    for (int i = 0; i < 4; ++i)
      af[i] = *(const half8*)&As[wr * 64 + i * 16 + fr][fk];
    #pragma unroll
    for (int j = 0; j < 4; ++j)
      bf[j] = *(const half8*)&Bs[wc * 64 + j * 16 + fr][fk];
    #pragma unroll
    for (int i = 0; i < 4; ++i)
      #pragma unroll
      for (int j = 0; j < 4; ++j)
        acc[i][j] = __builtin_amdgcn_mfma_f32_16x16x32_f16(af[i], bf[j], acc[i][j], 0, 0, 0);
    __syncthreads();
  }

  const int lr = (lane >> 4) * 4;   // C/D layout: col=lane&15, row=(lane>>4)*4+reg (m89)
  const int lc = lane & 15;
  if (Pk) {
    _Float16* dst = Pk + (size_t)blockIdx.z * MN;
    #pragma unroll
    for (int i = 0; i < 4; ++i)
      #pragma unroll
      for (int j = 0; j < 4; ++j)
        #pragma unroll
        for (int r = 0; r < 4; ++r) {
          int row = row0 + wr * 64 + i * 16 + lr + r;
          int col = col0 + wc * 64 + j * 16 + lc;
          dst[(size_t)row * ldc + col] = (_Float16)acc[i][j][r];
        }
    return;
  }
  #pragma unroll
  for (int i = 0; i < 4; ++i)
    #pragma unroll
    for (int j = 0; j < 4; ++j)
      #pragma unroll
      for (int r = 0; r < 4; ++r) {
        int row = row0 + wr * 64 + i * 16 + lr + r;
        int col = col0 + wc * 64 + j * 16 + lc;
        float v = acc[i][j][r];
        if (Cf) Cf[(size_t)row * ldc + col] = v;
        if (Ch) Ch[(size_t)row * ldc + col] = (_Float16)v;
      }
}

// ---------------- split-K reduce: Y = rowscale(row) * sum_z Pk[z]; writes f32/f16
__global__ __launch_bounds__(256)
void reduce_splitk(const _Float16* __restrict__ Pk, long MN, int S, int cshift,
                   const float* __restrict__ rowscale,
                   float* __restrict__ Yf, _Float16* __restrict__ Yh)
{
  long n4 = MN >> 2;
  for (long i = (long)blockIdx.x * 256 + threadIdx.x; i < n4; i += (long)gridDim.x * 256) {
    float s0 = 0, s1 = 0, s2 = 0, s3 = 0;
    for (int z = 0; z < S; ++z) {
      half4v p = ((const half4v*)(Pk + (size_t)z * MN))[i];
      s0 += (float)p[0]; s1 += (float)p[1]; s2 += (float)p[2]; s3 += (float)p[3];
    }
    if (rowscale) {
      float sc = rowscale[(i * 4) >> cshift];
      s0 *= sc; s1 *= sc; s2 *= sc; s3 *= sc;
    }
    if (Yf) {
      float4 o; o.x = s0; o.y = s1; o.z = s2; o.w = s3;
      ((float4*)Yf)[i] = o;
    }
    if (Yh) {
      half4v o;
      o[0] = (_Float16)s0; o[1] = (_Float16)s1; o[2] = (_Float16)s2; o[3] = (_Float16)s3;
      ((half4v*)Yh)[i] = o;
    }
  }
}

// ---------------- fused: degree row-sum -> dis, and f32 -> f16 adjacency convert
__global__ __launch_bounds__(256)
void degree_convert(const float* __restrict__ A, _Float16* __restrict__ Ah,
                    float* __restrict__ dis)
{
  const int row = blockIdx.x;
  const float* a = A + (size_t)row * NROW;
  _Float16* o = Ah + (size_t)row * NROW;
  float s = 0.f;
  #pragma unroll
  for (int it = 0; it < 6; ++it) {
    int j = it * 1024 + threadIdx.x * 4;
    float4 v = *(const float4*)&a[j];
    s += v.x + v.y + v.z + v.w;
    half4v h;
    h[0] = (_Float16)v.x; h[1] = (_Float16)v.y; h[2] = (_Float16)v.z; h[3] = (_Float16)v.w;
    *(half4v*)&o[j] = h;
  }
  #pragma unroll
  for (int off = 32; off; off >>= 1) s += __shfl_xor(s, off);
  __shared__ float red[4];
  if ((threadIdx.x & 63) == 0) red[threadIdx.x >> 6] = s;
  __syncthreads();
  if (threadIdx.x == 0) {
    float d = red[0] + red[1] + red[2] + red[3];
    dis[row] = (d > 0.f) ? rsqrtf(fmaxf(d, 1e-12f)) : 0.f;
  }
}

// ---------------- adj (f32 0/1) -> bitmask [NROW][192] u32
__global__ __launch_bounds__(192)
void build_mask(const float* __restrict__ adj, uint32_t* __restrict__ bits)
{
  const int row = blockIdx.x;
  const int w = threadIdx.x;   // 0..191
  const float* a = adj + (size_t)row * NROW + w * 32;
  uint32_t m = 0;
  #pragma unroll
  for (int q = 0; q < 8; ++q) {
    float4 x = *(const float4*)&a[q * 4];
    m |= (x.x != 0.f ? 1u : 0u) << (q * 4 + 0);
    m |= (x.y != 0.f ? 1u : 0u) << (q * 4 + 1);
    m |= (x.z != 0.f ? 1u : 0u) << (q * 4 + 2);
    m |= (x.w != 0.f ? 1u : 0u) << (q * 4 + 3);
  }
  bits[(size_t)row * 192 + w] = m;
}

// ---------------- f32 -> f16 convert with scale
__global__ __launch_bounds__(256)
void convert_f16(const float* __restrict__ x, _Float16* __restrict__ y, float scale, long n4)
{
  for (long i = (long)blockIdx.x * 256 + threadIdx.x; i < n4; i += (long)gridDim.x * 256) {
    float4 v = ((const float4*)x)[i];
    half4v o;
    o[0] = (_Float16)(v.x * scale);
    o[1] = (_Float16)(v.y * scale);
    o[2] = (_Float16)(v.z * scale);
    o[3] = (_Float16)(v.w * scale);
    ((half4v*)y)[i] = o;
  }
}

// ---------------- dst[c][r] = f16(src[r][c] * rowscale[r]); src f32 [R,C], dst [C,R]
__global__ __launch_bounds__(256)
void transpose_scale_f16(const float* __restrict__ src, const float* __restrict__ rowscale,
                         _Float16* __restrict__ dst, int R, int C)
{
  __shared__ _Float16 tile[64][72];
  const int c0 = blockIdx.x * 64, r0 = blockIdx.y * 64;
  const int tx4 = (threadIdx.x & 15) * 4, ty = threadIdx.x >> 4;
  #pragma unroll
  for (int p = 0; p < 4; ++p) {
    int r = p * 16 + ty;
    float4 v = *(const float4*)&src[(size_t)(r0 + r) * C + c0 + tx4];
    float sc = rowscale ? rowscale[r0 + r] : 1.0f;
    tile[tx4 + 0][r] = (_Float16)(v.x * sc);
    tile[tx4 + 1][r] = (_Float16)(v.y * sc);
    tile[tx4 + 2][r] = (_Float16)(v.z * sc);
    tile[tx4 + 3][r] = (_Float16)(v.w * sc);
  }
  __syncthreads();
  #pragma unroll
  for (int p = 0; p < 4; ++p) {
    int c = p * 16 + ty;
    half4v o;
    o[0] = tile[c][tx4 + 0];
    o[1] = tile[c][tx4 + 1];
    o[2] = tile[c][tx4 + 2];
    o[3] = tile[c][tx4 + 3];
    *(half4v*)&dst[(size_t)(c0 + c) * R + r0 + tx4] = o;
  }
}

// ---------------- dst[c][r] = src[r*ld + c]; f16 -> f16 transpose
__global__ __launch_bounds__(256)
void transpose_f16(const _Float16* __restrict__ src, int ld,
                   _Float16* __restrict__ dst, int R, int C)
{
  __shared__ _Float16 tile[64][72];
  const int c0 = blockIdx.x * 64, r0 = blockIdx.y * 64;
  const int tx4 = (threadIdx.x & 15) * 4, ty = threadIdx.x >> 4;
  #pragma unroll
  for (int p = 0; p < 4; ++p) {
    int r = p * 16 + ty;
    half4v v = *(const half4v*)&src[(size_t)(r0 + r) * ld + c0 + tx4];
    tile[tx4 + 0][r] = v[0];
    tile[tx4 + 1][r] = v[1];
    tile[tx4 + 2][r] = v[2];
    tile[tx4 + 3][r] = v[3];
  }
  __syncthreads();
  #pragma unroll
  for (int p = 0; p < 4; ++p) {
    int c = p * 16 + ty;
    half4v o;
    o[0] = tile[c][tx4 + 0];
    o[1] = tile[c][tx4 + 1];
    o[2] = tile[c][tx4 + 2];
    o[3] = tile[c][tx4 + 3];
    *(half4v*)&dst[(size_t)(c0 + c) * R + r0 + tx4] = o;
  }
}

// ---------------- in-place masked softmax over f16 scores; writes UNNORMALIZED exp
// and linv[row] = 1/sum (normalization folded into PV reduce rowscale)
__global__ __launch_bounds__(256)
void softmax_mask16(_Float16* __restrict__ Sf, const uint32_t* __restrict__ bits,
                    float* __restrict__ linv)
{
  const int row = blockIdx.x;
  _Float16* s = Sf + (size_t)row * NROW;
  const uint32_t* b = bits + (size_t)row * 192;
  const int tid = threadIdx.x;
  float v[24];
  float m = NEG_INF;
  #pragma unroll
  for (int it = 0; it < 3; ++it) {
    int j = it * 2048 + tid * 8;
    half8 sv = *(const half8*)&s[j];
    uint32_t w = (b[j >> 5] >> (j & 31)) & 0xffu;
    #pragma unroll
    for (int e = 0; e < 8; ++e) {
      float x = ((w >> e) & 1u) ? (float)sv[e] : NEG_INF;
      v[it * 8 + e] = x;
      m = fmaxf(m, x);
    }
  }
  #pragma unroll
  for (int off = 32; off; off >>= 1) m = fmaxf(m, __shfl_xor(m, off));
  __shared__ float red[4];
  const int lane = tid & 63, wave = tid >> 6;
  if (lane == 0) red[wave] = m;
  __syncthreads();
  m = fmaxf(fmaxf(red[0], red[1]), fmaxf(red[2], red[3]));
  __syncthreads();
  float l = 0.f;
  #pragma unroll
  for (int k = 0; k < 24; ++k) {
    float e = (v[k] == NEG_INF) ? 0.f : __expf(v[k] - m);
    v[k] = e; l += e;
  }
  #pragma unroll
  for (int off = 32; off; off >>= 1) l += __shfl_xor(l, off);
  if (lane == 0) red[wave] = l;
  __syncthreads();
  l = red[0] + red[1] + red[2] + red[3];
  if (tid == 0) linv[row] = (l > 0.f) ? (1.f / l) : 0.f;
  #pragma unroll
  for (int it = 0; it < 3; ++it) {
    int j = it * 2048 + tid * 8;
    half8 o;
    #pragma unroll
    for (int e = 0; e < 8; ++e) o[e] = (_Float16)v[it * 8 + e];
    *(half8*)&s[j] = o;
  }
}

// ---------------- BN partial sums over 128-row slices
__global__ __launch_bounds__(256)
void bn_partial(const float* __restrict__ X, int C,
                float* __restrict__ psum, float* __restrict__ psq)
{
  const int b = blockIdx.x;
  const int tid = threadIdx.x;
  const float* x = X + (size_t)b * 128 * C;
  float s0 = 0, q0 = 0, s1 = 0, q1 = 0;
  for (int r = 0; r < 128; ++r) {
    float a = x[(size_t)r * C + tid];
    s0 += a; q0 += a * a;
    if (C == 512) {
      float c2 = x[(size_t)r * C + tid + 256];
      s1 += c2; q1 += c2 * c2;
    }
  }
  psum[b * C + tid] = s0; psq[b * C + tid] = q0;
  if (C == 512) { psum[b * C + tid + 256] = s1; psq[b * C + tid + 256] = q1; }
}

__global__ void bn_finalize(const float* __restrict__ psum, const float* __restrict__ psq,
                            int C, const float* __restrict__ g, const float* __restrict__ beta,
                            float* __restrict__ scale, float* __restrict__ shift)
{
  int c = threadIdx.x + blockIdx.x * blockDim.x;
  if (c >= C) return;
  float s = 0, q = 0;
  for (int b = 0; b < 48; ++b) { s += psum[b * C + c]; q += psq[b * C + c]; }
  const float invN = 1.0f / 6144.0f;
  float mean = s * invN;
  float var = q * invN - mean * mean;
  float rstd = rsqrtf(fmaxf(var, 0.f) + 1e-5f);
  float sc = g[c] * rstd;
  scale[c] = sc;
  shift[c] = beta[c] - mean * sc;
}

// ---------------- y = relu?(x*scale[c]+shift[c]) + residual(f16); writes f32 and/or f16
__global__ __launch_bounds__(256)
void bn_apply(const float* __restrict__ X, const float* __restrict__ scale,
              const float* __restrict__ shift, const _Float16* __restrict__ residual,
              float* __restrict__ Yf, _Float16* __restrict__ Yh,
              int Cmask, long total, int do_relu)
{
  for (long i = (long)blockIdx.x * 256 + threadIdx.x; i < total; i += (long)gridDim.x * 256) {
    int c = (int)(i & Cmask);
    float v = X[i] * scale[c] + shift[c];
    if (do_relu) v = fmaxf(v, 0.f);
    if (residual) v += (float)residual[i];
    if (Yf) Yf[i] = v;
    if (Yh) Yh[i] = (_Float16)v;
  }
}

extern "C" void kernel_launch(void* const* d_in, const int* in_sizes, int n_in,
                              void* d_out, int out_size, void* d_ws, size_t ws_size,
                              hipStream_t stream)
{
  (void)in_sizes; (void)n_in; (void)out_size; (void)ws_size;
  const float* X     = (const float*)d_in[0];
  const float* adj   = (const float*)d_in[1];
  const float* adjg  = (const float*)d_in[2];
  const float* Wp    = (const float*)d_in[3];
  const float* gp    = (const float*)d_in[5];
  const float* betap = (const float*)d_in[6];

  float* out_h     = (float*)d_out;                       // [6144,256]
  float* out_embed = out_h + (size_t)NROW * DOUT;         // [6144,512]

  char* base = (char*)d_ws;
  size_t off = 0;
  auto alloc = [&](size_t bytes) -> void* {
    void* p = base + off;
    off += (bytes + 255) & ~(size_t)255;
    return p;
  };

  const long MN512 = (long)NROW * 512;

  _Float16* Ag  = (_Float16*)alloc((size_t)NROW * NROW * 2);   // adjg f16; reused as scores Sf
  _Float16* Sf  = Ag;
  uint32_t* bits = (uint32_t*)alloc((size_t)NROW * 192 * 4);
  _Float16* Pk  = (_Float16*)alloc((size_t)8 * MN512 * 2);     // split-K partials (f16)
  _Float16* XsT = (_Float16*)alloc((size_t)HDIM * NROW * 2);
  _Float16* Yh16 = (_Float16*)alloc((size_t)NROW * HDIM * 2);
  _Float16* Wph = (_Float16*)alloc((size_t)HDIM * HDIM * 2);
  _Float16* QKVW[3];
  for (int i = 0; i < 3; ++i) QKVW[i] = (_Float16*)alloc((size_t)1536 * HDIM * 2);
  _Float16* Woh[3];
  Woh[0] = (_Float16*)alloc((size_t)512 * 512 * 2);
  Woh[1] = (_Float16*)alloc((size_t)512 * 512 * 2);
  Woh[2] = (_Float16*)alloc((size_t)256 * 512 * 2);
  _Float16* QKVh = (_Float16*)alloc((size_t)NROW * 1536 * 2);
  _Float16* VTh  = (_Float16*)alloc((size_t)HDIM * NROW * 2);
  _Float16* AVh  = (_Float16*)alloc((size_t)NROW * HDIM * 2);
  float* xbuf = (float*)alloc((size_t)NROW * HDIM * 4);
  _Float16* hb16A = (_Float16*)alloc((size_t)NROW * HDIM * 2);
  _Float16* hb16B = (_Float16*)alloc((size_t)NROW * HDIM * 2);
  float* dis  = (float*)alloc((size_t)NROW * 4);
  float* linv = (float*)alloc((size_t)NROW * 4);
  float* psum = (float*)alloc((size_t)48 * 512 * 4);
  float* psq  = (float*)alloc((size_t)48 * 512 * 4);
  float* bnsc = (float*)alloc(512 * 4);
  float* bnsh = (float*)alloc(512 * 4);

  const float qk_scale = 0.21022410381342863f;  // 512^(-1/4); folded into both Wq and Wk

  degree_convert<<<NROW, 256, 0, stream>>>(adjg, Ag, dis);
  build_mask<<<NROW, 192, 0, stream>>>(adj, bits);
  transpose_scale_f16<<<dim3(8, 96), 256, 0, stream>>>(X, dis, XsT, NROW, HDIM);
  convert_f16<<<128, 256, 0, stream>>>(Wp, Wph, 1.f, 512 * 512 / 4);
  for (int i = 0; i < 3; ++i) {
    const float* Wq = (const float*)d_in[7 + i * 7 + 0];
    const float* Wk = (const float*)d_in[7 + i * 7 + 1];
    const float* Wv = (const float*)d_in[7 + i * 7 + 2];
    const float* Wo = (const float*)d_in[7 + i * 7 + 3];
    int o = (i < 2) ? 512 : 256;
    convert_f16<<<128, 256, 0, stream>>>(Wq, QKVW[i], qk_scale, 512 * 512 / 4);
    convert_f16<<<128, 256, 0, stream>>>(Wk, QKVW[i] + 512 * 512, qk_scale, 512 * 512 / 4);
    convert_f16<<<128, 256, 0, stream>>>(Wv, QKVW[i] + 2 * 512 * 512, 1.f, 512 * 512 / 4);
    convert_f16<<<128, 256, 0, stream>>>(Wo, Woh[i], 1.f, (long)o * 512 / 4);
  }

  // ---- embedding: h = BN( rowscale(dis) * (Ag @ XsT^T) @ Wp^T )   (bias cancels in BN)
  gemm_f16<<<dim3(48, 4, 8), 256, 0, stream>>>(Ag, NROW, XsT, NROW, nullptr, nullptr, 512,
                                               768, Pk, MN512);
  reduce_splitk<<<1536, 256, 0, stream>>>(Pk, MN512, 8, 9, dis, nullptr, Yh16);
  gemm_f16<<<dim3(48, 4), 256, 0, stream>>>(Yh16, HDIM, Wph, HDIM, xbuf, nullptr, HDIM,
                                            512, nullptr, 0);
  bn_partial<<<48, 256, 0, stream>>>(xbuf, 512, psum, psq);
  bn_finalize<<<2, 256, 0, stream>>>(psum, psq, 512, gp, betap, bnsc, bnsh);
  bn_apply<<<2048, 256, 0, stream>>>(xbuf, bnsc, bnsh, nullptr, out_embed, hb16A,
                                     511, MN512, 0);

  _Float16* hbuf[2] = {hb16A, hb16B};
  int cur = 0;
  for (int i = 0; i < 3; ++i) {
    int o = (i < 2) ? 512 : 256;
    const float* gl = (const float*)d_in[7 + i * 7 + 5];
    const float* bl = (const float*)d_in[7 + i * 7 + 6];
    _Float16* hin = hbuf[cur];

    // fused QKV projection: [6144,1536]
    gemm_f16<<<dim3(48, 12), 256, 0, stream>>>(hin, HDIM, QKVW[i], HDIM, nullptr, QKVh, 1536,
                                               512, nullptr, 0);
    transpose_f16<<<dim3(8, 96), 256, 0, stream>>>(QKVh + 1024, 1536, VTh, NROW, HDIM);
    // scores (full, f16) then in-place masked softmax (unnormalized exp + linv)
    gemm_f16<<<dim3(48, 48), 256, 0, stream>>>(QKVh, 1536, QKVh + 512, 1536, nullptr, Sf, NROW,
                                               512, nullptr, 0);
    softmax_mask16<<<NROW, 256, 0, stream>>>(Sf, bits, linv);
    // attn @ V (split-K 8), normalization via rowscale=linv in reduce
    gemm_f16<<<dim3(48, 4, 8), 256, 0, stream>>>(Sf, NROW, VTh, NROW, nullptr, nullptr, 512,
                                                 768, Pk, MN512);
    reduce_splitk<<<1536, 256, 0, stream>>>(Pk, MN512, 8, 9, linv, nullptr, AVh);
    // @ Wo^T (split-K 4; bias cancels in BN)
    long MNo = (long)NROW * o;
    gemm_f16<<<dim3(48, o / 128, 4), 256, 0, stream>>>(AVh, HDIM, Woh[i], HDIM,
                                                       nullptr, nullptr, o, 128, Pk, MNo);
    reduce_splitk<<<1536, 256, 0, stream>>>(Pk, MNo, 4, (o == 512) ? 9 : 8, nullptr,
                                            xbuf, nullptr);
    bn_partial<<<48, 256, 0, stream>>>(xbuf, o, psum, psq);
    bn_finalize<<<2, 256, 0, stream>>>(psum, psq, o, gl, bl, bnsc, bnsh);
    if (i < 2) {
      bn_apply<<<2048, 256, 0, stream>>>(xbuf, bnsc, bnsh, hin, nullptr, hbuf[cur ^ 1],
                                         o - 1, (long)NROW * o, 1);
      cur ^= 1;
    } else {
      bn_apply<<<2048, 256, 0, stream>>>(xbuf, bnsc, bnsh, nullptr, out_h, nullptr,
                                         o - 1, (long)NROW * o, 1);
    }
  }
}